// Round 11
// baseline (274.257 us; speedup 1.0000x reference)
//
#include <hip/hip_runtime.h>

#define DIM 128
#define EPS 1e-5f
#define SCAN_TILE 2048  // 256 threads x 8 elements
#define BROWS 64        // rows per fused-layer block

typedef short s16x8 __attribute__((ext_vector_type(8)));
typedef unsigned short u16x8 __attribute__((ext_vector_type(8)));
typedef float f32x4 __attribute__((ext_vector_type(4)));

__device__ __forceinline__ int lower_bound_i(const int* __restrict__ a, int n, int key) {
  int lo = 0, hi = n;
  while (lo < hi) {
    int mid = (lo + hi) >> 1;
    if (a[mid] < key) lo = mid + 1; else hi = mid;
  }
  return lo;
}

__device__ __forceinline__ unsigned rne_bf16(float f) {
  unsigned u = __builtin_bit_cast(unsigned, f);
  return (u + 0x7fffu + ((u >> 16) & 1u)) >> 16;
}
__device__ __forceinline__ float bf16_hi_to_f32(unsigned h) {
  return __builtin_bit_cast(float, h << 16);
}

// --- one kernel replaces all memsets ---------------------------------------
__global__ __launch_bounds__(256) void init_zero_kernel(float4* __restrict__ p, int n4) {
  int i = blockIdx.x * 256 + threadIdx.x;
  if (i < n4) p[i] = make_float4(0.f, 0.f, 0.f, 0.f);
}

// --- histogram + bf16 shadow of layer-1 activations (merged) ---------------
__global__ __launch_bounds__(256) void hist_cvt_kernel(const int* __restrict__ dst,
    int* __restrict__ cnt, const float* __restrict__ x,
    unsigned short* __restrict__ xh, int nE, int total8) {
  int i = blockIdx.x * 256 + threadIdx.x;
  if (i < nE) atomicAdd(&cnt[dst[i]], 1);
  if (i < total8) {
    float4 a = reinterpret_cast<const float4*>(x)[i * 2];
    float4 b = reinterpret_cast<const float4*>(x)[i * 2 + 1];
    u16x8 o;
    o[0] = (unsigned short)rne_bf16(a.x); o[1] = (unsigned short)rne_bf16(a.y);
    o[2] = (unsigned short)rne_bf16(a.z); o[3] = (unsigned short)rne_bf16(a.w);
    o[4] = (unsigned short)rne_bf16(b.x); o[5] = (unsigned short)rne_bf16(b.y);
    o[6] = (unsigned short)rne_bf16(b.z); o[7] = (unsigned short)rne_bf16(b.w);
    reinterpret_cast<u16x8*>(xh)[i] = o;
  }
}

// --- 3-phase scan ----------------------------------------------------------
__global__ __launch_bounds__(256) void scan1_kernel(const int* __restrict__ cnt,
                                                    int* __restrict__ bsum, int nN) {
  __shared__ int s[256];
  int t = threadIdx.x;
  int base = blockIdx.x * SCAN_TILE + t * 8;
  int sum = 0;
#pragma unroll
  for (int j = 0; j < 8; ++j) {
    int i = base + j;
    if (i < nN) sum += cnt[i];
  }
  s[t] = sum;
  __syncthreads();
  for (int off = 128; off > 0; off >>= 1) {
    if (t < off) s[t] += s[t + off];
    __syncthreads();
  }
  if (t == 0) bsum[blockIdx.x] = s[0];
}

__global__ __launch_bounds__(64) void scan2_kernel(int* __restrict__ bsum,
                                                   int* __restrict__ rowptr,
                                                   int nB, int nN) {
  if (threadIdx.x == 0) {
    int run = 0;
    for (int b = 0; b < nB; ++b) {
      int v = bsum[b];
      bsum[b] = run;
      run += v;
    }
    rowptr[nN] = run;
  }
}

__global__ __launch_bounds__(256) void scan3_kernel(const int* __restrict__ cnt,
                                                    const int* __restrict__ bsum,
                                                    int* __restrict__ rowptr, int nN) {
  __shared__ int s[256];
  int t = threadIdx.x;
  int base = blockIdx.x * SCAN_TILE + t * 8;
  int v[8];
  int tsum = 0;
#pragma unroll
  for (int j = 0; j < 8; ++j) {
    int i = base + j;
    v[j] = (i < nN) ? cnt[i] : 0;
    tsum += v[j];
  }
  s[t] = tsum;
  __syncthreads();
  for (int off = 1; off < 256; off <<= 1) {
    int u = (t >= off) ? s[t - off] : 0;
    __syncthreads();
    s[t] += u;
    __syncthreads();
  }
  int run = bsum[blockIdx.x] + ((t > 0) ? s[t - 1] : 0);
#pragma unroll
  for (int j = 0; j < 8; ++j) {
    int i = base + j;
    if (i < nN) rowptr[i] = run;
    run += v[j];
  }
}

__global__ __launch_bounds__(256) void fill_kernel(const int* __restrict__ src,
    const int* __restrict__ dst, const int* __restrict__ rowptr,
    int* __restrict__ cursor, int* __restrict__ eidx, int nE) {
  int e = blockIdx.x * 256 + threadIdx.x;
  if (e < nE) {
    int d = dst[e];
    int p = atomicAdd(&cursor[d], 1);
    eidx[rowptr[d] + p] = src[e];
  }
}

// --- W prep: both layers in one launch -------------------------------------
__global__ __launch_bounds__(256) void cvt_w_kernel(const float* __restrict__ W_l,
    const float* __restrict__ W_r, unsigned short* __restrict__ Wth,
    unsigned short* __restrict__ Wtl, int nL) {
  int idx = blockIdx.x * 256 + threadIdx.x;  // l*DIM*256 + c*256 + k
  if (idx >= nL * DIM * 256) return;
  int l = idx / (DIM * 256);
  int rem = idx - l * DIM * 256;
  int c = rem >> 8, k = rem & 255;
  const float* Wl = W_l + (size_t)l * DIM * DIM;
  const float* Wr = W_r + (size_t)l * DIM * DIM;
  float v = (k < DIM) ? Wl[(size_t)k * DIM + c] : Wr[(size_t)(k - DIM) * DIM + c];
  unsigned h = rne_bf16(v);
  float r = v - bf16_hi_to_f32(h);
  Wth[idx] = (unsigned short)h;
  Wtl[idx] = (unsigned short)rne_bf16(r);
}

// --- fused layer: gather-mean -> dual GEMM (MFMA) -> BN stats ---------------
// Block: 64 rows x 128 cols, 256 threads = 4 waves (wave tile 16x128).
// LDS 80KB: A0 agg tile 16KB (XOR-swizzled bf16) | Wh 32KB | Wl 32KB.
// Phase 0: gather-mean neighbors into A0. Phases s=0,1: stage W half, MFMA
// (s=0 A from LDS A0; s=1 A = root row from global xh). Epilogue: store h
// (bf16) + per-block column sum/sumsq -> global atomics (s_sum aliases A0).
__global__ __launch_bounds__(256) void fused_layer_kernel(
    const unsigned short* __restrict__ xsrc,
    const int* __restrict__ rowptr, const int* __restrict__ eidx,
    const unsigned short* __restrict__ Wth, const unsigned short* __restrict__ Wtl,
    const float* __restrict__ bias, unsigned short* __restrict__ h,
    float* __restrict__ sums, int nN) {
  __shared__ __align__(16) char lds_raw[81920];
  char* Whb = lds_raw + 16384;
  char* Wlb = lds_raw + 49152;
  float* s_sum = (float*)lds_raw;            // epilogue alias of A0
  float* s_sq  = (float*)(lds_raw + 512);

  const int tid = threadIdx.x;
  const int lane = tid & 63;
  const int wave = tid >> 6;
  const int nbase = blockIdx.x * BROWS;

  // ---- phase 0: gather-mean into A0 ----------------------------------------
  {
    int j = tid & 15;     // 16B chunk (8 cols)
    int rg = tid >> 4;    // 0..15
#pragma unroll
    for (int p = 0; p < 4; ++p) {
      int r_loc = p * 16 + rg;
      int r = nbase + r_loc;
      float acc[8] = {0.f, 0.f, 0.f, 0.f, 0.f, 0.f, 0.f, 0.f};
      float invd = 0.f;
      if (r < nN) {
        int lo = rowptr[r], hi2 = rowptr[r + 1];
        int i = lo;
        for (; i + 3 < hi2; i += 4) {
          int s0 = eidx[i], s1 = eidx[i + 1], s2 = eidx[i + 2], s3 = eidx[i + 3];
          u16x8 v0 = *reinterpret_cast<const u16x8*>(xsrc + (size_t)s0 * DIM + j * 8);
          u16x8 v1 = *reinterpret_cast<const u16x8*>(xsrc + (size_t)s1 * DIM + j * 8);
          u16x8 v2 = *reinterpret_cast<const u16x8*>(xsrc + (size_t)s2 * DIM + j * 8);
          u16x8 v3 = *reinterpret_cast<const u16x8*>(xsrc + (size_t)s3 * DIM + j * 8);
#pragma unroll
          for (int q = 0; q < 8; ++q) {
            acc[q] += bf16_hi_to_f32(v0[q]) + bf16_hi_to_f32(v1[q]);
            acc[q] += bf16_hi_to_f32(v2[q]) + bf16_hi_to_f32(v3[q]);
          }
        }
        for (; i < hi2; ++i) {
          int s0 = eidx[i];
          u16x8 v0 = *reinterpret_cast<const u16x8*>(xsrc + (size_t)s0 * DIM + j * 8);
#pragma unroll
          for (int q = 0; q < 8; ++q) acc[q] += bf16_hi_to_f32(v0[q]);
        }
        invd = 1.0f / fmaxf((float)(hi2 - lo), 1.0f);
      }
      u16x8 o;
#pragma unroll
      for (int q = 0; q < 8; ++q) o[q] = (unsigned short)rne_bf16(acc[q] * invd);
      int lb = r_loc * 256 + ((j * 16) ^ ((r_loc & 7) << 4));
      *reinterpret_cast<u16x8*>(lds_raw + lb) = o;
    }
  }
  // (A0 writes ordered before A0 reads by the two staging barriers below)

  const int lrow = lane & 15;
  const int koff = (lane >> 4) * 8;
  const int row_loc = wave * 16 + lrow;
  int r0 = nbase + row_loc; if (r0 > nN - 1) r0 = nN - 1;

  f32x4 acc[8];
#pragma unroll
  for (int ct = 0; ct < 8; ++ct) acc[ct] = (f32x4){0.f, 0.f, 0.f, 0.f};

#pragma unroll
  for (int s = 0; s < 2; ++s) {
    __syncthreads();  // prior phase's LDS reads (and phase-0 A0 writes) done
#pragma unroll
    for (int i = 0; i < 8; ++i) {
      int idx = i * 256 + tid;   // 0..2047
      int c = idx >> 4;
      int kc = idx & 15;
      int lb = c * 256 + ((kc * 16) ^ ((c & 7) << 4));
      float4 hv = *reinterpret_cast<const float4*>(Wth + (size_t)c * 256 + s * 128 + kc * 8);
      float4 lv = *reinterpret_cast<const float4*>(Wtl + (size_t)c * 256 + s * 128 + kc * 8);
      *reinterpret_cast<float4*>(Whb + lb) = hv;
      *reinterpret_cast<float4*>(Wlb + lb) = lv;
    }
    __syncthreads();

#pragma unroll
    for (int ks = 0; ks < 4; ++ks) {
      int ka = ks * 32 + koff;
      s16x8 a;
      if (s == 0) {
        int lb = row_loc * 256 + ((ka * 2) ^ ((row_loc & 7) << 4));
        a = *reinterpret_cast<const s16x8*>(lds_raw + lb);
      } else {
        a = *reinterpret_cast<const s16x8*>(xsrc + (size_t)r0 * DIM + ka);
      }
#pragma unroll
      for (int ct = 0; ct < 8; ++ct) {
        int c = ct * 16 + lrow;
        int lb = c * 256 + ((ka * 2) ^ ((c & 7) << 4));
        s16x8 wh = *reinterpret_cast<const s16x8*>(Whb + lb);
        s16x8 wl = *reinterpret_cast<const s16x8*>(Wlb + lb);
        acc[ct] = __builtin_amdgcn_mfma_f32_16x16x32_bf16(a, wh, acc[ct], 0, 0, 0);
        acc[ct] = __builtin_amdgcn_mfma_f32_16x16x32_bf16(a, wl, acc[ct], 0, 0, 0);
      }
    }
  }

  // epilogue: store h (bf16) and accumulate BN stats (s_sum aliases dead A0)
  if (tid < DIM) { s_sum[tid] = 0.f; s_sq[tid] = 0.f; }
  __syncthreads();
  float csum[8], csq[8];
#pragma unroll
  for (int ct = 0; ct < 8; ++ct) { csum[ct] = 0.f; csq[ct] = 0.f; }
#pragma unroll
  for (int ct = 0; ct < 8; ++ct) {
    int c = ct * 16 + lrow;
    float b = bias[c];
    int rr = nbase + wave * 16 + (lane >> 4) * 4;
#pragma unroll
    for (int j = 0; j < 4; ++j) {
      int row = rr + j;
      if (row < nN) {
        float v = acc[ct][j] + b;
        h[(size_t)row * DIM + c] = (unsigned short)rne_bf16(v);
        csum[ct] += v;
        csq[ct] += v * v;
      }
    }
  }
#pragma unroll
  for (int ct = 0; ct < 8; ++ct) {
    csum[ct] += __shfl_xor(csum[ct], 16);
    csum[ct] += __shfl_xor(csum[ct], 32);
    csq[ct]  += __shfl_xor(csq[ct], 16);
    csq[ct]  += __shfl_xor(csq[ct], 32);
  }
  if (lane < 16) {
#pragma unroll
    for (int ct = 0; ct < 8; ++ct) {
      atomicAdd(&s_sum[ct * 16 + lane], csum[ct]);
      atomicAdd(&s_sq[ct * 16 + lane], csq[ct]);
    }
  }
  __syncthreads();
  if (tid < DIM) {
    atomicAdd(&sums[tid], s_sum[tid]);
    atomicAdd(&sums[DIM + tid], s_sq[tid]);
  }
}

// BN+ReLU: bf16 h in, bf16 activations out (8 elems/thread).
__global__ __launch_bounds__(256) void bn_relu_kernel(const unsigned short* __restrict__ h,
    const float* __restrict__ sums, const float* __restrict__ gamma,
    const float* __restrict__ beta, unsigned short* __restrict__ xhout, int nN) {
  int idx = blockIdx.x * 256 + threadIdx.x;
  int total = nN * (DIM / 8);
  if (idx >= total) return;
  int c = (idx & 15) * 8;
  float invN = 1.0f / (float)nN;
  u16x8 hv = reinterpret_cast<const u16x8*>(h)[idx];
  u16x8 oh;
#pragma unroll
  for (int j = 0; j < 8; ++j) {
    float mu = sums[c + j] * invN;
    float var = sums[DIM + c + j] * invN - mu * mu;
    float sc = gamma[c + j] * rsqrtf(var + EPS);
    float sh = beta[c + j] - mu * sc;
    float v = fmaxf(bf16_hi_to_f32(hv[j]) * sc + sh, 0.0f);
    oh[j] = (unsigned short)rne_bf16(v);
  }
  reinterpret_cast<u16x8*>(xhout)[idx] = oh;
}

// --- fused final BN+ReLU + segmented mean-pool ------------------------------
#define POOL_ROWS 32
__global__ __launch_bounds__(256) void pool_fused_kernel(const unsigned short* __restrict__ h,
    const float* __restrict__ sums, const float* __restrict__ gamma,
    const float* __restrict__ beta, const int* __restrict__ batch,
    float* __restrict__ outsum, int nN) {
  int c = threadIdx.x & 127;
  int rp = threadIdx.x >> 7;
  int r0 = blockIdx.x * POOL_ROWS;
  float invN = 1.0f / (float)nN;
  float mu = sums[c] * invN;
  float var = sums[DIM + c] * invN - mu * mu;
  float sc = gamma[c] * rsqrtf(var + EPS);
  float sh = beta[c] - mu * sc;
  int rend = min(r0 + POOL_ROWS, nN);
  float acc = 0.f;
  int cur = -1;
  for (int r = r0 + rp; r < rend; r += 2) {
    int g = batch[r];
    float v = fmaxf(bf16_hi_to_f32(h[(size_t)r * DIM + c]) * sc + sh, 0.0f);
    if (g != cur) {
      if (cur >= 0) atomicAdd(&outsum[(size_t)cur * DIM + c], acc);
      cur = g; acc = 0.f;
    }
    acc += v;
  }
  if (cur >= 0) atomicAdd(&outsum[(size_t)cur * DIM + c], acc);
}

__global__ __launch_bounds__(256) void pool_div_kernel(const float* __restrict__ outsum,
    const int* __restrict__ batch, float* __restrict__ out, int nN, int nG) {
  int idx = blockIdx.x * 256 + threadIdx.x;  // g*128 + c
  if (idx >= nG * DIM) return;
  int g = idx >> 7;
  int lo = lower_bound_i(batch, nN, g);
  int hi = lower_bound_i(batch, nN, g + 1);
  float cnt = fmaxf((float)(hi - lo), 1.0f);
  out[idx] = outsum[idx] / cnt;
}

extern "C" void kernel_launch(void* const* d_in, const int* in_sizes, int n_in,
                              void* d_out, int out_size, void* d_ws, size_t ws_size,
                              hipStream_t stream) {
  const float* x     = (const float*)d_in[0];
  const int*   ei    = (const int*)d_in[1];
  const int*   batch = (const int*)d_in[2];
  const float* W_l   = (const float*)d_in[3];
  const float* b_l   = (const float*)d_in[4];
  const float* W_r   = (const float*)d_in[5];
  const float* gamma = (const float*)d_in[6];
  const float* beta  = (const float*)d_in[7];
  float* out = (float*)d_out;

  const int N = in_sizes[2];
  const int E = in_sizes[1] / 2;
  const int G = out_size / DIM;
  const int L = in_sizes[3] / (DIM * DIM);

  const int* src  = ei;
  const int* dstE = ei + E;

  const int nB = (N + SCAN_TILE - 1) / SCAN_TILE;

  // workspace layout (zeroed region contiguous: cnt|cursor|sums(L)|outsum)
  char* wsb = (char*)d_ws;
  unsigned short* h    = (unsigned short*)wsb; wsb += (size_t)N * DIM * sizeof(unsigned short);
  unsigned short* xh   = (unsigned short*)wsb; wsb += (size_t)N * DIM * sizeof(unsigned short);
  unsigned short* Wth  = (unsigned short*)wsb; wsb += (size_t)L * DIM * 256 * sizeof(unsigned short);
  unsigned short* Wtl  = (unsigned short*)wsb; wsb += (size_t)L * DIM * 256 * sizeof(unsigned short);
  char* zbase = wsb;
  int* cnt      = (int*)wsb;    wsb += (size_t)N * sizeof(int);
  int* cursor   = (int*)wsb;    wsb += (size_t)N * sizeof(int);
  float* sums   = (float*)wsb;  wsb += (size_t)L * 2 * DIM * sizeof(float);
  float* outsum = (float*)wsb;  wsb += (size_t)G * DIM * sizeof(float);
  int zbytes = (int)((char*)wsb - zbase);
  int* rowptr = (int*)wsb;      wsb += (size_t)(N + 1) * sizeof(int);
  int* bsum   = (int*)wsb;      wsb += (size_t)nB * sizeof(int);
  int* eidx   = (int*)wsb;      wsb += (size_t)E * sizeof(int);

  // 1. zero region (one node)
  int n4 = zbytes / 16;
  init_zero_kernel<<<(n4 + 255) / 256, 256, 0, stream>>>((float4*)zbase, n4);
  // 2. histogram + bf16 shadow of x
  int total8 = N * (DIM / 8);
  int histcvt_n = max(E, total8);
  hist_cvt_kernel<<<(histcvt_n + 255) / 256, 256, 0, stream>>>(dstE, cnt, x, xh, E, total8);
  // 3-5. scan
  scan1_kernel<<<nB, 256, 0, stream>>>(cnt, bsum, N);
  scan2_kernel<<<1, 64, 0, stream>>>(bsum, rowptr, nB, N);
  scan3_kernel<<<nB, 256, 0, stream>>>(cnt, bsum, rowptr, N);
  // 6. CSR fill
  fill_kernel<<<(E + 255) / 256, 256, 0, stream>>>(src, dstE, rowptr, cursor, eidx, E);
  // 7. W prep, both layers
  cvt_w_kernel<<<(L * DIM * 256 + 255) / 256, 256, 0, stream>>>(W_l, W_r, Wth, Wtl, L);

  for (int l = 0; l < L; ++l) {
    fused_layer_kernel<<<(N + BROWS - 1) / BROWS, 256, 0, stream>>>(xh, rowptr, eidx,
        Wth + (size_t)l * DIM * 256, Wtl + (size_t)l * DIM * 256,
        b_l + (size_t)l * DIM, h, sums + (size_t)l * 2 * DIM, N);
    if (l < L - 1) {
      bn_relu_kernel<<<(N * (DIM / 8) + 255) / 256, 256, 0, stream>>>(
          h, sums + (size_t)l * 2 * DIM, gamma + (size_t)l * DIM,
          beta + (size_t)l * DIM, xh, N);
    } else {
      pool_fused_kernel<<<(N + POOL_ROWS - 1) / POOL_ROWS, 256, 0, stream>>>(
          h, sums + (size_t)l * 2 * DIM, gamma + (size_t)l * DIM,
          beta + (size_t)l * DIM, batch, outsum, N);
      pool_div_kernel<<<(G * DIM + 255) / 256, 256, 0, stream>>>(outsum, batch, out, N, G);
    }
  }
}